// Round 7
// baseline (881.840 us; speedup 1.0000x reference)
//
#include <hip/hip_runtime.h>
#include <stdint.h>
#include <math.h>

typedef __attribute__((ext_vector_type(8))) short s16x8;
typedef __attribute__((ext_vector_type(4))) short s16x4;
typedef __attribute__((ext_vector_type(4))) float f32x4;

#define NEGH (-1.0e30f)

__device__ __forceinline__ short f2bf(float f) {
  union { float f; unsigned int i; } c; c.f = f;
  unsigned int lsb = (c.i >> 16) & 1u;
  c.i += 0x7fffu + lsb;
  return (short)(c.i >> 16);
}
__device__ __forceinline__ float bf2f(short u) {
  union { unsigned int i; float f; } c;
  c.i = ((unsigned int)(unsigned short)u) << 16;
  return c.f;
}

// async global->LDS, 16B per lane. LDS dest must be wave-uniform base + lane*16.
#define GLOAD_LDS16(gp, lp)                                                  \
  __builtin_amdgcn_global_load_lds(                                          \
      (__attribute__((address_space(1))) void*)(void*)(gp),                  \
      (__attribute__((address_space(3))) void*)(lp), 16, 0, 0)

// ---------------------------------------------------------------------------
// fp32 -> bf16 conversion, 4 elements/thread. n must be divisible by 1024.
// ---------------------------------------------------------------------------
__global__ __launch_bounds__(256) void cvt_kernel(const float* __restrict__ in,
                                                  short* __restrict__ out)
{
  const size_t i = ((size_t)blockIdx.x * 256 + threadIdx.x) * 4;
  const float4 v = *(const float4*)(in + i);
  s16x4 o = { f2bf(v.x), f2bf(v.y), f2bf(v.z), f2bf(v.w) };
  *(s16x4*)(out + i) = o;
}

// ---------------------------------------------------------------------------
// GEMM: C[M,N] = A[M,K] * W[N,K]^T + bias[N]   (A,W bf16; bias fp32; fp32 acc)
// 128x128 tile, BK=64, 256 threads (4 waves in 2x2), mfma 16x16x32 bf16.
// omode: 0 = bf16 C row-major; 1 = fp32 C row-major;
//        2 = bf16 scatter C^T as vt[(b*N + n)*2048 + s] with m = b*2048+s.
// ---------------------------------------------------------------------------
__global__ __launch_bounds__(256) void gemm_bt(
    const short* __restrict__ A, const short* __restrict__ W,
    const float* __restrict__ bias, void* __restrict__ C,
    int M, int N, int K, int omode)
{
  __shared__ __align__(16) short As[128 * 64];
  __shared__ __align__(16) short Bs[128 * 64];

  const int t = threadIdx.x;
  const int l = t & 63;
  const int w = t >> 6;
  const int lane16 = l & 15;
  const int quad = l >> 4;
  const int wm = w >> 1, wn = w & 1;
  const int mb0 = blockIdx.y * 128;
  const int nb0 = blockIdx.x * 128;

  const f32x4 zero = {0.f, 0.f, 0.f, 0.f};
  f32x4 acc[4][4];
#pragma unroll
  for (int i = 0; i < 4; ++i)
#pragma unroll
    for (int j = 0; j < 4; ++j) acc[i][j] = zero;

  // staging geometry: per issue 256 threads cover 32 rows x 8 segs(16B)
  const int sr = t >> 3;                 // row within 32-row issue block
  const int sp = t & 7;                  // 16B segment within row
  const short* Ag = A + (size_t)(mb0 + sr) * K + sp * 8;
  const short* Wg = W + (size_t)(nb0 + sr) * K + sp * 8;
  short* Al = As + t * 8;
  short* Bl = Bs + t * 8;

  const int nkt = K >> 6;
  for (int kt = 0; kt < nkt; ++kt) {
    __syncthreads();
    const int kof = kt * 64;
#pragma unroll
    for (int it = 0; it < 4; ++it) {
      GLOAD_LDS16(Ag + kof + (size_t)(it * 32) * K, Al + it * 2048);
      GLOAD_LDS16(Wg + kof + (size_t)(it * 32) * K, Bl + it * 2048);
    }
    __syncthreads();
#pragma unroll
    for (int kk = 0; kk < 2; ++kk) {
      s16x8 af[4], bf[4];
#pragma unroll
      for (int mi = 0; mi < 4; ++mi)
        af[mi] = *(const s16x8*)&As[(wm * 64 + mi * 16 + lane16) * 64 +
                                    kk * 32 + quad * 8];
#pragma unroll
      for (int ni = 0; ni < 4; ++ni)
        bf[ni] = *(const s16x8*)&Bs[(wn * 64 + ni * 16 + lane16) * 64 +
                                    kk * 32 + quad * 8];
#pragma unroll
      for (int mi = 0; mi < 4; ++mi)
#pragma unroll
        for (int ni = 0; ni < 4; ++ni)
          acc[mi][ni] = __builtin_amdgcn_mfma_f32_16x16x32_bf16(
              af[mi], bf[ni], acc[mi][ni], 0, 0, 0);
    }
  }

  // epilogue: C/D layout col=lane&15 (n), row=quad*4+reg (m)
#pragma unroll
  for (int ni = 0; ni < 4; ++ni) {
    const int n = nb0 + wn * 64 + ni * 16 + lane16;
    const float bv = bias[n];
#pragma unroll
    for (int mi = 0; mi < 4; ++mi) {
      const int m0 = mb0 + wm * 64 + mi * 16 + quad * 4;
#pragma unroll
      for (int r = 0; r < 4; ++r) {
        const int m = m0 + r;
        const float v = acc[mi][ni][r] + bv;
        if (omode == 0) {
          ((short*)C)[(size_t)m * N + n] = f2bf(v);
        } else if (omode == 1) {
          ((float*)C)[(size_t)m * N + n] = v;
        } else {
          // m = b*2048 + s ; vt[(b*N + n)*2048 + s]
          ((short*)C)[((size_t)(m >> 11) * N + n) * 2048 + (m & 2047)] = f2bf(v);
        }
      }
    }
  }
}

// ---------------------------------------------------------------------------
// RoPE in place on bf16 buf[row][head*128 + d], pairs (d, d+64), pos = row%2048.
// Accurate sincosf (arg reaches 2047 rad; native v_sin domain ends ~±804).
// ---------------------------------------------------------------------------
__global__ __launch_bounds__(256) void rope_kernel(short* __restrict__ buf,
                                                   int lognh)
{
  const int idx = blockIdx.x * 256 + threadIdx.x;
  const int d = idx & 63;
  const int rest = idx >> 6;            // row*nh + h
  const int row = rest >> lognh;
  const int pos = row & 2047;
  // inv_freq = 10000^(-d/64) = exp2(-d * log2(10000)/64)
  const float fr = (float)pos * exp2f((float)d * -0.20762050593048584f);
  float sn, cs;
  sincosf(fr, &sn, &cs);
  const size_t base = (size_t)rest * 128 + d;
  const float lo = bf2f(buf[base]);
  const float hi = bf2f(buf[base + 64]);
  buf[base]      = f2bf(lo * cs - hi * sn);
  buf[base + 64] = f2bf(hi * cs + lo * sn);
}

// ---------------------------------------------------------------------------
// Flash attention, causal, GQA (kv = h>>2). Block: 64 q-rows for one (b,h);
// 4 waves, each a 16-row q strip. St = K*Q^T (both LDS-contiguous), online
// softmax in St C-layout (q = lane&15), P->A-frag via wave-private LDS
// round-trip, PV from pre-transposed V (vt[b][kv][d][s]). All bf16 in/out.
// In-place og==qg safe: each block reads only its own Q rows (into regs,
// before its only stores); blocks touch disjoint (row, head-col) cells.
// ---------------------------------------------------------------------------
__global__ __launch_bounds__(256) void attn_kernel(
    const short* __restrict__ qg, const short* __restrict__ kg,
    const short* __restrict__ vtg, short* __restrict__ og)
{
  __shared__ __align__(16) short Ksm[64 * 136];   // [key][d], pad 136
  __shared__ __align__(16) short Vsm[128 * 72];   // [d][key], pad 72
  __shared__ __align__(16) short Psm[64 * 72];    // [q(64)][key], pad 72

  const int t = threadIdx.x;
  const int l = t & 63;
  const int w = t >> 6;
  const int lane16 = l & 15;
  const int quad = l >> 4;
  const int qt = blockIdx.x, h = blockIdx.y, b = blockIdx.z;
  const int kv = h >> 2;
  const int qb0 = qt * 64;
  const int qw0 = qb0 + w * 16;

  // Q B-fragments (Q^T operand): lane holds Q[q=lane16][d=kk*32+quad*8+j]
  s16x8 qf[4];
  {
    const short* qrow =
        qg + ((size_t)(b * 2048 + qw0 + lane16)) * 2048 + h * 128 + quad * 8;
#pragma unroll
    for (int kk = 0; kk < 4; ++kk) qf[kk] = *(const s16x8*)(qrow + kk * 32);
  }

  const f32x4 zero = {0.f, 0.f, 0.f, 0.f};
  f32x4 o[8];
#pragma unroll
  for (int i = 0; i < 8; ++i) o[i] = zero;
  float m_i = NEGH, l_i = 0.f;

  const float SC = 0.08838834764831845f * 1.4426950408889634f; // rsqrt(128)*log2e

  const int ntiles = qt + 1;
  for (int itl = 0; itl < ntiles; ++itl) {
    const int kbase = itl * 64;
    __syncthreads();
    // stage K tile [64 keys][128 d]
#pragma unroll
    for (int j = 0; j < 4; ++j) {
      const int L = j * 256 + t;
      const int r = L >> 4, sg2 = L & 15;
      *(uint4*)&Ksm[r * 136 + sg2 * 8] =
          *(const uint4*)(kg + ((size_t)(b * 2048 + kbase + r)) * 512 +
                          kv * 128 + sg2 * 8);
    }
    // stage Vt tile [128 d][64 keys]
#pragma unroll
    for (int j = 0; j < 4; ++j) {
      const int L = j * 256 + t;
      const int dd = L >> 3, sg2 = L & 7;
      *(uint4*)&Vsm[dd * 72 + sg2 * 8] =
          *(const uint4*)(vtg + ((size_t)(b * 512 + kv * 128 + dd)) * 2048 +
                          kbase + sg2 * 8);
    }
    __syncthreads();

    // St = K_tile(64x128) * Q^T(128x16): C col=q=lane16, row=key=quad*4+r
    f32x4 st[4];
#pragma unroll
    for (int mt = 0; mt < 4; ++mt) st[mt] = zero;
#pragma unroll
    for (int mt = 0; mt < 4; ++mt)
#pragma unroll
      for (int kk = 0; kk < 4; ++kk) {
        s16x8 a = *(const s16x8*)&Ksm[(mt * 16 + lane16) * 136 + kk * 32 + quad * 8];
        st[mt] = __builtin_amdgcn_mfma_f32_16x16x32_bf16(a, qf[kk], st[mt], 0, 0, 0);
      }

    // online softmax (folded scale*log2e); masks finite -1e30
    const bool lastt = (itl == ntiles - 1);
    const int qabs = qw0 + lane16;
    float tl = NEGH;
#pragma unroll
    for (int mt = 0; mt < 4; ++mt)
#pragma unroll
      for (int r = 0; r < 4; ++r) {
        float xx = st[mt][r] * SC;
        if (lastt && (kbase + mt * 16 + quad * 4 + r) > qabs) xx = NEGH;
        st[mt][r] = xx;
        tl = fmaxf(tl, xx);
      }
    tl = fmaxf(tl, __shfl_xor(tl, 16));
    tl = fmaxf(tl, __shfl_xor(tl, 32));
    const float mnew = fmaxf(m_i, tl);
    const float alpha = exp2f(m_i - mnew);
    float rs = 0.f;
#pragma unroll
    for (int mt = 0; mt < 4; ++mt) {
      const float p0 = exp2f(st[mt][0] - mnew);
      const float p1 = exp2f(st[mt][1] - mnew);
      const float p2 = exp2f(st[mt][2] - mnew);
      const float p3 = exp2f(st[mt][3] - mnew);
      rs += (p0 + p1) + (p2 + p3);
      s16x4 pk = { f2bf(p0), f2bf(p1), f2bf(p2), f2bf(p3) };
      *(s16x4*)&Psm[(w * 16 + lane16) * 72 + mt * 16 + quad * 4] = pk;
    }
    rs += __shfl_xor(rs, 16);
    rs += __shfl_xor(rs, 32);
    l_i = l_i * alpha + rs;
    m_i = mnew;

    // rescale O (O rows are q = quad*4+r; alpha lives at lane16=q)
#pragma unroll
    for (int r = 0; r < 4; ++r) {
      const float ar = __shfl(alpha, quad * 4 + r);
#pragma unroll
      for (int nt = 0; nt < 8; ++nt) o[nt][r] *= ar;
    }

    // PV: O[q][d] += P[q][key] * Vt[d][key]
#pragma unroll
    for (int kk = 0; kk < 2; ++kk) {
      s16x8 pf = *(const s16x8*)&Psm[(w * 16 + lane16) * 72 + kk * 32 + quad * 8];
#pragma unroll
      for (int nt = 0; nt < 8; ++nt) {
        s16x8 vf = *(const s16x8*)&Vsm[(nt * 16 + lane16) * 72 + kk * 32 + quad * 8];
        o[nt] = __builtin_amdgcn_mfma_f32_16x16x32_bf16(pf, vf, o[nt], 0, 0, 0);
      }
    }
  }

  // normalize and store: O row q = quad*4+r, col d = nt*16+lane16
#pragma unroll
  for (int r = 0; r < 4; ++r) {
    const float lr = __shfl(l_i, quad * 4 + r);
    const float inv = 1.f / lr;
    const size_t base =
        ((size_t)(b * 2048 + qw0 + quad * 4 + r)) * 2048 + h * 128 + lane16;
#pragma unroll
    for (int nt = 0; nt < 8; ++nt) og[base + nt * 16] = f2bf(o[nt][r] * inv);
  }
}

// ---------------------------------------------------------------------------
extern "C" void kernel_launch(void* const* d_in, const int* in_sizes, int n_in,
                              void* d_out, int out_size, void* d_ws,
                              size_t ws_size, hipStream_t stream)
{
  const float* x  = (const float*)d_in[0];
  const float* wq = (const float*)d_in[1];
  const float* bq = (const float*)d_in[2];
  const float* wk = (const float*)d_in[3];
  const float* bk = (const float*)d_in[4];
  const float* wv = (const float*)d_in[5];
  const float* bv = (const float*)d_in[6];
  const float* wo = (const float*)d_in[7];
  const float* bo = (const float*)d_in[8];
  float* out = (float*)d_out;

  // ws layout (76 MiB used; ws_size >= 80 MiB proven by round-5 probe):
  //   xb  @0      32 MiB  [8192][2048] bf16; dead after V-proj -> wob reuses @0
  //   wqb @32MiB   8 MiB  [2048][2048] bf16
  //   wkb @40MiB   2 MiB  [512][2048]  bf16
  //   wvb @42MiB   2 MiB  [512][2048]  bf16
  //   qws @44MiB  32 MiB  [8192][2048] bf16; attention output in place
  // d_out (64 MiB fp32) doubles as scratch for K / Vt (dead before final GEMM):
  //   kws @out+0   8 MiB  [8192][512]  bf16
  //   vtw @out+8M  8 MiB  [b][kv*128][2048] bf16
  char* ws = (char*)d_ws;
  short* xb  = (short*)ws;
  short* wqb = (short*)(ws + (32ull << 20));
  short* wkb = (short*)(ws + (40ull << 20));
  short* wvb = (short*)(ws + (42ull << 20));
  short* qws = (short*)(ws + (44ull << 20));
  short* wob = xb;
  short* kws = (short*)d_out;
  short* vtw = (short*)((char*)d_out + (8ull << 20));

  const dim3 blk(256);
  // fp32 -> bf16 input conversions
  cvt_kernel<<<16384, blk, 0, stream>>>(x,  xb);   // 16.7M elems
  cvt_kernel<<<4096,  blk, 0, stream>>>(wq, wqb);  // 4.19M
  cvt_kernel<<<1024,  blk, 0, stream>>>(wk, wkb);  // 1.05M
  cvt_kernel<<<1024,  blk, 0, stream>>>(wv, wvb);  // 1.05M
  // projections (bf16 MFMA, fp32 bias)
  gemm_bt<<<dim3(16, 64), blk, 0, stream>>>(xb, wqb, bq, qws, 8192, 2048, 2048, 0);
  gemm_bt<<<dim3(4, 64),  blk, 0, stream>>>(xb, wkb, bk, kws, 8192, 512, 2048, 0);
  gemm_bt<<<dim3(4, 64),  blk, 0, stream>>>(xb, wvb, bv, vtw, 8192, 512, 2048, 2);
  // rope (q: nh=16 -> lognh 4; k: nh=4 -> lognh 2); v untouched
  rope_kernel<<<32768, blk, 0, stream>>>(qws, 4);
  rope_kernel<<<8192,  blk, 0, stream>>>(kws, 2);
  // wo conversion into xb's slot (xb dead after V-proj; stream-ordered)
  cvt_kernel<<<4096, blk, 0, stream>>>(wo, wob);   // 4.19M
  // attention (in place on qws)
  attn_kernel<<<dim3(32, 16, 4), blk, 0, stream>>>(qws, kws, vtw, qws);
  // output projection: fp32 C into d_out (kws/vtw dead now)
  gemm_bt<<<dim3(16, 64), blk, 0, stream>>>(qws, wob, bo, out, 8192, 2048, 2048, 1);
}